// Round 17
// baseline (74.207 us; speedup 1.0000x reference)
//
#include <hip/hip_runtime.h>
#include <math.h>

// ConnectedLossV4, 3-node graph, two-phase connected components.
// R16 passed at 74us. This round removes the last big LDS-atomic serialization:
// k_argmax_uf issued ~512 same-word LDS atomicAdds per wave for class/target
// counts (8 hot words, ~32-way serialization) + 256/block for nA/nB. Now:
// per-thread counts packed into 16-bit fields of two uint64 (max 256/wave fits),
// shfl-reduced across the wave, lane0 does <=32 LDS atomics/wave. nA/nB also
// shfl-reduced.
// Structure (R14-R16):
//   1 k_argmax_uf block0 zeros stats+ghist; per 64x16 tile: argmax + continuous
//                 bg term + LDS union-find (89% of edges intra-tile) + local
//                 flatten -> parent[]=global root seed; per-block partials +
//                 local-link counts (plain stores).
//   2 k_bmerge    ~78K tile-boundary edges: global CAS-unite on seeded parent
//                 (plain cached ops; benign races per R11-R14 analysis); AS
//                 link partials; last-arriving block reduces ALL partials ->
//                 scalars (ncomp = cnt - links_local - links_boundary).
//   3 k_phase2    scalars plain; root chase (plain cached, ~1-2 hops); keys in
//                 registers; exact-code hist (ballot-aggregated bin0, 257-pad)
//                 -> per-(blockIdx&7) ghist replica -> arrive -> non-last exit
//                 -> last block: replica-sum + 7-thread scan -> bce+dice.
// ws layout (verified non-overlapping):
//   stats[0,8192) ghist[8192,24576) pcnt[24576,45056) mcnt[45056,53248)
//   pdbl[53248,59392) bcnt[59392,61440).

#define HWMASK (262144 - 1)
#define AL(p) __hip_atomic_load((p), __ATOMIC_RELAXED, __HIP_MEMORY_SCOPE_AGENT)
#define AS(p, v) __hip_atomic_store((p), (v), __ATOMIC_RELAXED, __HIP_MEMORY_SCOPE_AGENT)
#define REL(p, v) __hip_atomic_store((p), (v), __ATOMIC_RELEASE, __HIP_MEMORY_SCOPE_AGENT)
#define ARRIVE(p) __hip_atomic_fetch_add((p), 1u, __ATOMIC_RELAXED, __HIP_MEMORY_SCOPE_AGENT)

// ---- global UF (boundary edges only) -------------------------------------
static __device__ __forceinline__ int ufind(int* p, int x) {
  while (true) {
    int px = p[x];
    if (px == x) return x;
    int g = p[px];
    if (g == px) return px;
    p[x] = g;  // halving: target non-root, value ancestor -> benign
    x = g;
  }
}
static __device__ __forceinline__ int unite(int* p, int a, int b) {
  while (true) {
    a = ufind(p, a); b = ufind(p, b);
    if (a == b) return 0;
    if (a < b) { int old = atomicCAS(&p[b], b, a); if (old == b) return 1; b = old; }
    else       { int old = atomicCAS(&p[a], a, b); if (old == a) return 1; a = old; }
  }
}
// ---- LDS UF (intra-tile) ---------------------------------------------------
static __device__ __forceinline__ int lfind(int* p, int x) {
  while (true) {
    int px = p[x];
    if (px == x) return x;
    int g = p[px];
    if (g == px) return px;
    p[x] = g;
    x = g;
  }
}
static __device__ __forceinline__ int lunite(int* p, int a, int b) {
  while (true) {
    a = lfind(p, a); b = lfind(p, b);
    if (a == b) return 0;
    if (a < b) { int old = atomicCAS(&p[b], b, a); if (old == b) return 1; b = old; }
    else       { int old = atomicCAS(&p[a], a, b); if (old == a) return 1; a = old; }
  }
}

// One 64x16 tile per block; thread t owns 4 px: lx=(t&15)*4, ly=t>>4.
__global__ __launch_bounds__(256) void k_argmax_uf(
    const float* __restrict__ pred, const int* __restrict__ tgt,
    int* __restrict__ parent, unsigned char* __restrict__ pk,
    unsigned* __restrict__ stats, unsigned* __restrict__ pcnt,
    unsigned* __restrict__ mcnt, double* __restrict__ pdbl, int N) {
  __shared__ int slab[1024];
  __shared__ unsigned char scls[1024];
  __shared__ unsigned hc8[8], ht8[8], lcnt[8], hA, hB;
  __shared__ double dred[12];
  int tid = threadIdx.x, bid = blockIdx.x;
  if (bid == 0) {     // zero stats[0..8191] + ghist[16384] = 24576 words
    uint4* z = (uint4*)stats;
    for (int j = tid; j < 6144; j += 256) z[j] = make_uint4(0u, 0u, 0u, 0u);
  }
  if (tid < 8) { hc8[tid] = 0; ht8[tid] = 0; lcnt[tid] = 0; }
  if (tid == 0) { hA = 0; hB = 0; }
  __syncthreads();
  // tile coords: 8 tile-cols x 32 tile-rows per image, 256 tiles/image
  int img = bid >> 8, trow = (bid & 255) >> 3, tcol = bid & 7;
  int ly = tid >> 4, lx4 = (tid & 15) << 2;
  int lj = (ly << 6) + lx4;                       // local idx of first px
  int gy = (trow << 4) + ly, gx = (tcol << 6) + lx4;
  int gi = (img << 18) + (gy << 9) + gx;
  const float* pp = pred + ((size_t)img << 21) + (gy << 9) + gx;
  float4 v[8];
#pragma unroll
  for (int ch = 0; ch < 8; ++ch) v[ch] = *(const float4*)(pp + ((size_t)ch << 18));
  int4 tv = *(const int4*)(tgt + gi);
  int tarr[4] = {tv.x & 7, tv.y & 7, tv.z & 7, tv.w & 7};
  unsigned char pkb[4], carr[4];
  double aL = 0.0, aI = 0.0, aP = 0.0;
  unsigned nA = 0, nB = 0;
  unsigned long long pc0 = 0, pc1 = 0, pt0 = 0, pt1 = 0;  // 16-bit x4 fields
#pragma unroll
  for (int j = 0; j < 4; ++j) {
    float p0 = ((const float*)&v[0])[j];
    float best = p0; int c = 0;
#pragma unroll
    for (int ch = 1; ch < 8; ++ch) {              // first-max == numpy argmax
      float x = ((const float*)&v[ch])[j];
      if (x > best) { best = x; c = ch; }
    }
    int t = tarr[j];
    carr[j] = (unsigned char)c;
    pkb[j] = (unsigned char)(c | (t << 3));
    if (c < 4) pc0 += 1ull << (c << 4); else pc1 += 1ull << ((c - 4) << 4);
    if (t < 4) pt0 += 1ull << (t << 4); else pt1 += 1ull << ((t - 4) << 4);
    if (c == 0) {                                 // continuous bg term
      float pc = fminf(fmaxf(p0, 1e-7f), 1.0f - 1e-7f);
      if (t == 0) { aL += (double)logf(pc); aI += (double)p0; }
      else        { aL += (double)logf(1.0f - pc); }
      aP += (double)p0;
    } else { if (t == 0) nA++; else nB++; }       // pv==0 -> constant, count
  }
  *(uchar4*)(pk + gi) = make_uchar4(pkb[0], pkb[1], pkb[2], pkb[3]);
  *(uchar4*)(scls + lj) = make_uchar4(carr[0], carr[1], carr[2], carr[3]);
  *(int4*)(slab + lj) = make_int4(lj, lj + 1, lj + 2, lj + 3);
  // wave-reduce packed counters + nA/nB (no per-pixel LDS atomics)
#pragma unroll
  for (int o = 32; o > 0; o >>= 1) {
    pc0 += __shfl_down(pc0, o); pc1 += __shfl_down(pc1, o);
    pt0 += __shfl_down(pt0, o); pt1 += __shfl_down(pt1, o);
    nA += __shfl_down(nA, o);   nB += __shfl_down(nB, o);
  }
  int lane = tid & 63;
  if (lane == 0) {
#pragma unroll
    for (int q = 0; q < 4; ++q) {
      unsigned a = (unsigned)((pc0 >> (q << 4)) & 0xFFFFull);
      unsigned b = (unsigned)((pc1 >> (q << 4)) & 0xFFFFull);
      unsigned c = (unsigned)((pt0 >> (q << 4)) & 0xFFFFull);
      unsigned d = (unsigned)((pt1 >> (q << 4)) & 0xFFFFull);
      if (a) atomicAdd(&hc8[q], a);
      if (b) atomicAdd(&hc8[4 + q], b);
      if (c) atomicAdd(&ht8[q], c);
      if (d) atomicAdd(&ht8[4 + q], d);
    }
    if (nA) atomicAdd(&hA, nA);
    if (nB) atomicAdd(&hB, nB);
  }
  __syncthreads();
  // ---- local UF over intra-tile edges ------------------------------------
#pragma unroll
  for (int k = 0; k < 3; ++k)                     // intra-quad right edges
    if (carr[k] && carr[k] == carr[k + 1] && lunite(slab, lj + k, lj + k + 1))
      atomicAdd(&lcnt[carr[k]], 1u);
  if (lx4 < 60) {                                 // quad-boundary right edge
    unsigned char nc = scls[lj + 4];
    if (carr[3] && carr[3] == nc && lunite(slab, lj + 3, lj + 4))
      atomicAdd(&lcnt[carr[3]], 1u);
  }
  if (ly < 15) {                                  // down edges
#pragma unroll
    for (int k = 0; k < 4; ++k) {
      unsigned char nc = scls[lj + 64 + k];
      if (carr[k] && carr[k] == nc && lunite(slab, lj + k, lj + 64 + k))
        atomicAdd(&lcnt[carr[k]], 1u);
    }
  }
  __syncthreads();
  // ---- local flatten -> global root seed ---------------------------------
  int pout[4];
#pragma unroll
  for (int k = 0; k < 4; ++k) {
    pout[k] = gi + k;
    if (carr[k]) {
      int r = slab[lj + k];
      while (true) { int nx = slab[r]; if (nx == r) break; r = nx; }
      pout[k] = (img << 18) + (((trow << 4) + (r >> 6)) << 9) + (tcol << 6) + (r & 63);
    }
  }
  *(int4*)(parent + gi) = make_int4(pout[0], pout[1], pout[2], pout[3]);
#pragma unroll
  for (int o = 32; o > 0; o >>= 1) {
    aL += __shfl_down(aL, o); aI += __shfl_down(aI, o); aP += __shfl_down(aP, o);
  }
  int wid = tid >> 6;
  if (lane == 0) { dred[wid] = aL; dred[4 + wid] = aI; dred[8 + wid] = aP; }
  __syncthreads();
  // per-block partials: plain stores (boundary flush publishes)
  if (tid < 8) {
    pcnt[bid * 20 + tid]     = hc8[tid];
    pcnt[bid * 20 + 8 + tid] = ht8[tid];
    mcnt[bid * 8 + tid] = lcnt[tid];
  }
  if (tid == 0) {
    pcnt[bid * 20 + 16] = hA; pcnt[bid * 20 + 17] = hB;
    pcnt[bid * 20 + 18] = 0u; pcnt[bid * 20 + 19] = 0u;
    pdbl[bid * 3 + 0] = dred[0] + dred[1] + dred[2] + dred[3];
    pdbl[bid * 3 + 1] = dred[4] + dred[5] + dred[6] + dred[7];
    pdbl[bid * 3 + 2] = dred[8] + dred[9] + dred[10] + dred[11];
  }
}

// Boundary edges: x=63 mod 64 (right) and y=15 mod 16 (down). ~78K edges.
__global__ __launch_bounds__(256) void k_bmerge(
    const unsigned char* __restrict__ pk, int* __restrict__ parent,
    unsigned* __restrict__ stats, const unsigned* __restrict__ pcnt,
    const unsigned* __restrict__ mcnt, unsigned* __restrict__ bcnt,
    int N, int nbam) {
  __shared__ unsigned lcnt[8], tot[26];
  __shared__ int lastM;
  int tid = threadIdx.x, bid = blockIdx.x;
  if (tid < 8) lcnt[tid] = 0;
  __syncthreads();
  int B = N >> 18;
  int Eh = B * 3584;                   // 7 x-boundaries x 512 rows per image
  int E = Eh + B * 15872;              // + 31 y-boundaries x 512 cols
  int gsz = gridDim.x * blockDim.x;
  for (int e = bid * blockDim.x + tid; e < E; e += gsz) {
    int gi1, gi2;
    if (e < Eh) {
      int img = e / 3584, rem = e % 3584;
      int x = ((rem >> 9) << 6) + 63, y = rem & 511;
      gi1 = (img << 18) + (y << 9) + x; gi2 = gi1 + 1;
    } else {
      int e2 = e - Eh;
      int img = e2 / 15872, rem = e2 % 15872;
      int y = ((rem >> 9) << 4) + 15, x = rem & 511;
      gi1 = (img << 18) + (y << 9) + x; gi2 = gi1 + 512;
    }
    int c1 = pk[gi1] & 7;
    if (c1 && c1 == (pk[gi2] & 7) && unite(parent, gi1, gi2))
      atomicAdd(&lcnt[c1], 1u);
  }
  __syncthreads();
  if (tid < 8) AS(&bcnt[bid * 8 + tid], lcnt[tid]);   // -> LLC (same-kernel read)
  __syncthreads();   // drain vmcnt before arrive
  if (tid == 0) lastM = (ARRIVE(&stats[76]) == gridDim.x - 1) ? 1 : 0;
  __syncthreads();
  if (!lastM) return;                                  // no spinning
  // ---- last block: reduce partials + scalars ----------------------------
  unsigned S[26];
#pragma unroll
  for (int k = 0; k < 26; ++k) S[k] = 0u;
  for (int b = tid; b < nbam; b += 256) {
    const unsigned* p = pcnt + b * 20;
#pragma unroll
    for (int k = 0; k < 18; ++k) S[k] += p[k];         // plain: post-boundary
#pragma unroll
    for (int k = 0; k < 8; ++k) S[18 + k] += mcnt[b * 8 + k];  // local links
  }
  for (int b = tid; b < (int)gridDim.x; b += 256)      // boundary links (AL)
#pragma unroll
    for (int k = 0; k < 8; ++k) S[18 + k] += AL(&bcnt[b * 8 + k]);
  if (tid < 26) tot[tid] = 0u;
  __syncthreads();
#pragma unroll
  for (int k = 0; k < 26; ++k) {
    unsigned s = S[k];
#pragma unroll
    for (int o = 32; o > 0; o >>= 1) s += __shfl_down(s, o);
    if ((tid & 63) == 0 && s) atomicAdd(&tot[k], s);
  }
  __syncthreads();
  if (tid != 0) return;
  // scalars (single thread); plain stores -- boundary flush publishes
  float prodf[8]; int last_i = 1; unsigned pb = 0;
  for (int v = 1; v < 8; ++v) {
    unsigned cntv = tot[v];
    unsigned ncv = cntv - tot[18 + v];   // ncomp = cnt - successful links
    prodf[v] = 0.0f;
    if (cntv) {
      prodf[v] = __fmul_rn((float)ncv, (float)last_i);     // exact ref rounding
      pb |= 1u << v;
      last_i += (int)ncv + ((cntv < (unsigned)N) ? 1 : 0); // + has_bg
    }
    stats[24 + v] = __float_as_uint(prodf[v]);
  }
  float ph0 = 0.0f;   // background key (min key: rounding is monotone)
  for (int v = 1; v < 8; ++v) if (pb & (1u << v)) ph0 = __fadd_rn(ph0, prodf[v]);
  unsigned ab = 0;
  for (int t = 0; t < 8; ++t) stats[8 + t] = tot[8 + t];
  for (int t = 1; t < 8; ++t) {
    unsigned n = tot[8 + t];
    stats[48 + t] = n ? ((n - 1) >> 1) : 0u;   // lower-median rank
    if (n) ab |= 1u << t;
  }
  stats[32] = pb; stats[33] = ab;
  stats[34] = tot[16]; stats[35] = tot[17];
  unsigned pbits = __float_as_uint(ph0);
  stats[36] = pbits;
  // key-code window bound: codes in (ph0, ph0+2^20] <= 2^(43-e) + margin
  unsigned c;
  if (pbits == 0) c = 64u;
  else {
    int e = (int)(pbits >> 23) - 127;
    int sh = 43 - e;
    if (sh <= 0) c = 64u;
    else if (sh >= 31) c = 0x7FFFFFFFu;
    else c = (1u << sh) + 64u;
  }
  int bl = 32 - __clz((int)c);
  stats[37] = (bl > 8) ? (unsigned)(bl - 8) : 0u;   // s1 for 8-bit digits
}

// Fallback-path scan: pick bin holding rank krem[t], update prefix.
static __device__ void scan_select(unsigned* __restrict__ stats,
                                   const unsigned* __restrict__ ghist,
                                   unsigned abm, int s_cur, unsigned* lh) {
  int tid = threadIdx.x;
  for (int t = 1; t < 8; ++t) {
    if (!(abm >> t & 1u)) continue;
    int k = (int)AL(&stats[48 + t]);
    unsigned cnt = 0;
#pragma unroll
    for (int r = 0; r < 8; ++r)
      cnt += AL(&ghist[r * 2048 + (t << 8) + tid]);
    lh[tid] = cnt;
    __syncthreads();
    for (int o = 1; o < 256; o <<= 1) {   // inclusive Hillis-Steele
      unsigned v = (tid >= o) ? lh[tid - o] : 0u;
      __syncthreads();
      lh[tid] += v;
      __syncthreads();
    }
    unsigned incl = lh[tid], excl = incl - cnt;
    if ((unsigned)k >= excl && (unsigned)k < incl) {   // unique owner
      atomicOr(&stats[40 + t], ((unsigned)tid) << s_cur);
      AS(&stats[48 + t], (unsigned)(k - (int)excl));
    }
    __syncthreads();
  }
}

static __device__ void finalize_loss(unsigned* __restrict__ stats,
                                     const double* __restrict__ pdbl,
                                     float* __restrict__ out, int N, int nbam,
                                     unsigned ab, double* dred) {
  int tid = threadIdx.x;
  double vL = 0.0, vI = 0.0, vP = 0.0;
  for (int b = tid; b < nbam; b += 256) {
    vL += pdbl[b * 3]; vI += pdbl[b * 3 + 1]; vP += pdbl[b * 3 + 2];
  }
#pragma unroll
  for (int o = 32; o > 0; o >>= 1) {
    vL += __shfl_down(vL, o); vI += __shfl_down(vI, o); vP += __shfl_down(vP, o);
  }
  int wid = tid >> 6, lane = tid & 63;
  if (lane == 0) { dred[wid] = vL; dred[4 + wid] = vI; dred[8 + wid] = vP; }
  __syncthreads();
  if (tid != 0) return;
  vL = dred[0] + dred[1] + dred[2] + dred[3];
  vI = dred[4] + dred[5] + dred[6] + dred[7];
  vP = dred[8] + dred[9] + dred[10] + dred[11];
  double Nd = (double)N;
  const float e32 = 1e-7f;
  const float c1 = 1.0f - e32;
  const float omc1 = 1.0f - c1;
  double lp1 = log((double)c1);
  double lp0 = log((double)e32);
  double l01 = log((double)omc1);
  double l00 = lp1;
  double L = vL + (double)stats[34] * lp0 + (double)stats[35] * l00;
  double res = -L / Nd;                                                // bce_bg
  res += 1.0 - (2.0 * vI + 1.0) / (vP + (double)stats[8] + 1.0);       // dice_bg
  for (int t = 1; t < 8; ++t) {
    if (ab >> t & 1u) {
      double a = (double)AL(&stats[56 + t]);   // n11
      double f = (double)AL(&stats[64 + t]);   // |full_med|
      double n = (double)stats[8 + t];
      double bce = -(a * lp1 + (n - a) * lp0 + (f - a) * l01 + (Nd - n - f + a) * l00) / Nd;
      double dice = 1.0 - (2.0 * a + 1.0) / (f + n + 1.0);
      res += bce + dice;
    }
  }
  int nu = 0;
  for (int t = 0; t < 8; ++t) nu += (stats[8 + t] > 0) ? 1 : 0;
  out[0] = (float)(res / ((double)nu + 1.0));
}

__global__ __launch_bounds__(256, 4) void k_phase2(
    const unsigned char* __restrict__ pk, const int* __restrict__ parent,
    unsigned* __restrict__ stats, unsigned* __restrict__ ghist,
    const double* __restrict__ pdbl, float* __restrict__ out, int N, int nbam) {
  __shared__ unsigned lh[2176];    // main: lh[t*257+bin] (banks differ per t)
  __shared__ float sprod[8];
  __shared__ unsigned sw[32];
  __shared__ double dred[12];
  int tid = threadIdx.x;
  int lane = tid & 63;
  if (tid < 8) sprod[tid] = __uint_as_float(stats[24 + tid]);   // post-boundary
  if (tid == 0) { sw[0] = stats[32]; sw[1] = stats[33]; sw[2] = stats[36]; sw[3] = stats[37]; }
  for (int j = tid; j < 2176; j += 256) lh[j] = 0u;
  __syncthreads();
  unsigned pb = sw[0], ab = sw[1], ph0 = sw[2];
  int s1 = (int)sw[3];
  unsigned rep = (blockIdx.x & 7) * 2048u;
  int n4 = N >> 2;
  // ---- root chase + keys (registers) + exact-code hist -------------------
  unsigned kk[4];
  unsigned char tv8[4], binv[4];
  int i4 = blockIdx.x * blockDim.x + tid;   // one quad per thread
  if (i4 < n4) {
    int i = i4 << 2;
    int4 pr = *(const int4*)(parent + i);
    uchar4 pv = *(const uchar4*)(pk + i);
    int parr[4] = {pr.x, pr.y, pr.z, pr.w};
    unsigned char pa[4] = {pv.x, pv.y, pv.z, pv.w};
#pragma unroll
    for (int j = 0; j < 4; ++j) {
      int c = pa[j] & 7, t = pa[j] >> 3;
      float lab = 0.0f;
      if (c) {
        int x = parr[j];
        while (true) { int nx = parent[x]; if (nx == x) break; x = nx; }
        lab = (float)(x + 1);                    // < 2^24, exact
      }
      float ph = 0.0f;
#pragma unroll
      for (int v = 1; v < 8; ++v) {              // exact numpy op order
        if (pb & (1u << v)) {
          float term = sprod[v];
          if (c == v) term = __fadd_rn(lab, term);
          ph = __fadd_rn(ph, term);
        }
      }
      unsigned kb = __float_as_uint(ph);
      kk[j] = kb; tv8[j] = (unsigned char)t;
      unsigned off = kb - ph0;                   // >= 0 by monotonicity
      unsigned bin = off >> s1;
      if (bin > 255u) bin = 255u;
      binv[j] = (unsigned char)bin;
    }
  } else {
#pragma unroll
    for (int j = 0; j < 4; ++j) { kk[j] = 0xFFFFFFFFu; tv8[j] = 0; binv[j] = 255; }
  }
  // hist adds: ballot-aggregate bin==0 (bg majority); rare bins individually.
#pragma unroll
  for (int e = 0; e < 4; ++e) {
    bool act = (i4 < n4);
    unsigned bin = binv[e];
    int t = tv8[e];
    bool b0 = act && (bin == 0u);
    unsigned long long m0 = __ballot(b0);
    if (b0) {
      if (lane == (int)__ffsll(m0) - 1) atomicAdd(&lh[0], (unsigned)__popcll(m0));
    } else if (act) {
      atomicAdd(&lh[bin], 1u);
    }
#pragma unroll
    for (int tt = 1; tt < 8; ++tt) {
      if (!(ab >> tt & 1u)) continue;
      unsigned long long mt = __ballot(b0 && t == tt);
      if (mt && lane == (int)__ffsll(mt) - 1)
        atomicAdd(&lh[tt * 257], (unsigned)__popcll(mt));
    }
    if (act && bin != 0u && t && (ab >> t & 1u))
      atomicAdd(&lh[t * 257 + bin], 1u);
  }
  __syncthreads();
  for (int j = tid; j < 2048; j += 256) {        // flush: 257-stride -> packed
    unsigned v = lh[(j >> 8) * 257 + (j & 255)];
    if (v) atomicAdd(&ghist[rep + j], v);
  }
  __syncthreads();
  if (tid == 0) sw[4] = (ARRIVE(&stats[77]) == gridDim.x - 1) ? 1u : 0u;
  __syncthreads();
  if (s1 == 0) {
    // ==== COMMON PATH: bins are exact codes ================================
    if (!sw[4]) return;                          // non-last blocks exit
    for (int j = tid; j < 2048; j += 256) {      // parallel 8-replica sum
      unsigned s = 0;
#pragma unroll
      for (int r = 0; r < 8; ++r) s += AL(&ghist[r * 2048 + j]);
      lh[j] = s;                                 // packed (t<<8|bin) layout
    }
    __syncthreads();
    if (tid >= 1 && tid < 8 && (ab >> tid & 1u)) {   // 7 independent scanners
      int t = tid;
      unsigned k = stats[48 + t];
      unsigned cum = 0;
      int mb = 255;
      for (int b = 0; b < 256; ++b) {
        unsigned c = lh[(t << 8) + b];
        if (cum + c > k) { mb = b; break; }
        cum += c;
      }
      AS(&stats[56 + t], lh[(t << 8) + mb]);     // n11 = hist[t][med_bin]
      AS(&stats[64 + t], lh[mb]);                // nfm = histAll[med_bin]
    }
    __syncthreads();                             // drain AS before AL reads
    finalize_loss(stats, pdbl, out, N, nbam, ab, dred);
    return;
  }
  // ==== FALLBACK (s1 > 0): multi-pass radix + med-match, spin barriers ====
  if (sw[4]) {
    scan_select(stats, ghist, ab, s1, lh);
    for (int j = tid; j < 16384; j += 256) AS(&ghist[j], 0u);
    __syncthreads();
    if (tid == 0) REL(&stats[39], 1u);
  } else {
    if (tid == 0) while (AL(&stats[39]) < 1u) __builtin_amdgcn_s_sleep(2);
    __syncthreads();
  }
  for (int pass = 2; pass <= 4; ++pass) {
    int sprev = s1 - 8 * (pass - 2); if (sprev < 0) sprev = 0;
    int scur  = s1 - 8 * (pass - 1); if (scur  < 0) scur  = 0;
    unsigned maskhi = 0xFFFFFFFFu << sprev;
    if (tid < 8) sw[8 + tid] = AL(&stats[40 + tid]);
    for (int j = tid; j < 2048; j += 256) lh[j] = 0u;
    __syncthreads();
#pragma unroll
    for (int e = 0; e < 4; ++e) {
      int t = tv8[e];
      if (t && (ab >> t & 1u)) {
        unsigned off = kk[e] - ph0;
        if (((off ^ sw[8 + t]) & maskhi) == 0u)
          atomicAdd(&lh[(t << 8) | ((off >> scur) & 255u)], 1u);
      }
    }
    __syncthreads();
    for (int j = tid; j < 2048; j += 256) {
      unsigned v = lh[j];
      if (v) atomicAdd(&ghist[rep + j], v);
    }
    __syncthreads();
    if (tid == 0) sw[5] = (ARRIVE(&stats[76 + pass]) == gridDim.x - 1) ? 1u : 0u;
    __syncthreads();
    if (sw[5]) {
      scan_select(stats, ghist, ab, scur, lh);
      if (scur > 0)
        for (int j = tid; j < 16384; j += 256) AS(&ghist[j], 0u);
      __syncthreads();
      if (tid == 0) REL(&stats[39], (unsigned)pass);
    } else {
      if (tid == 0)
        while (AL(&stats[39]) < (unsigned)pass) __builtin_amdgcn_s_sleep(2);
      __syncthreads();
    }
    if (scur == 0) break;
  }
  // med-match counts from register keys
  if (tid < 16) lh[tid] = 0u;
  if (tid < 8) sw[20 + tid] = ph0 + AL(&stats[40 + tid]);
  __syncthreads();
#pragma unroll
  for (int e = 0; e < 4; ++e) {
    unsigned kb = kk[e];
    int t = tv8[e];
#pragma unroll
    for (int tt = 1; tt < 8; ++tt) {
      if ((ab >> tt & 1u) && kb == sw[20 + tt]) {
        atomicAdd(&lh[8 + tt], 1u);
        if (t == tt) atomicAdd(&lh[tt], 1u);
      }
    }
  }
  __syncthreads();
  if (tid >= 1 && tid < 8) {
    if (lh[8 + tid]) atomicAdd(&stats[64 + tid], lh[8 + tid]);   // nfm
    if (lh[tid])     atomicAdd(&stats[56 + tid], lh[tid]);       // n11
  }
  __syncthreads();
  if (tid == 0) sw[6] = (ARRIVE(&stats[84]) == gridDim.x - 1) ? 1u : 0u;
  __syncthreads();
  if (!sw[6]) return;
  finalize_loss(stats, pdbl, out, N, nbam, ab, dred);
}

extern "C" void kernel_launch(void* const* d_in, const int* in_sizes, int n_in,
                              void* d_out, int out_size, void* d_ws, size_t ws_size,
                              hipStream_t stream) {
  const float* pred = (const float*)d_in[0];   // [B,8,512,512] f32
  const int* tgt = (const int*)d_in[1];        // [B,1,512,512] i32
  int N = in_sizes[1];                         // B*H*W, H=W=512
  char* ws = (char*)d_ws;
  int* parent = (int*)ws;
  unsigned char* pk = (unsigned char*)(ws + (size_t)N * 4);
  unsigned* stats = (unsigned*)(ws + (size_t)N * 5);
  unsigned* ghist = stats + 8192;
  unsigned* pcnt = stats + 24576;
  unsigned* mcnt = stats + 45056;              // [45056, 53248)
  double* pdbl = (double*)(stats + 53248);     // [53248, 59392)
  unsigned* bcnt = stats + 59392;              // [59392, 61440)
  float* out = (float*)d_out;
  int nbam = N >> 10;                          // 64x16 tiles (1024 px) = 1024
  int nblk2 = ((N >> 2) + 255) >> 8;           // one quad per thread

  k_argmax_uf<<<nbam, 256, 0, stream>>>(pred, tgt, parent, pk, stats, pcnt, mcnt, pdbl, N);
  k_bmerge<<<256, 256, 0, stream>>>(pk, parent, stats, pcnt, mcnt, bcnt, N, nbam);
  k_phase2<<<nblk2, 256, 0, stream>>>(pk, parent, stats, ghist, pdbl, out, N, nbam);
}

// Round 18
// 74.108 us; speedup vs baseline: 1.0013x; 1.0013x over previous
//
#include <hip/hip_runtime.h>
#include <math.h>

// ConnectedLossV4, 3-node graph, two-phase connected components.
// R17 null (74.2 == 74.1): counter aggregation wasn't the binding constraint.
// This round targets k_argmax_uf's latency hiding + VALU:
//  (a) __launch_bounds__(256,4): cap VGPR<=128 -> 4 blocks/CU (16 waves/CU).
//  (b) single-logf: sum(log pc | t=0) + sum(log(1-pc) | t!=0) = log(prod),
//      one f32 product per thread (>=1e-28, no underflow; summed in double
//      downstream, threshold slack is huge) -> 1 logf/thread instead of ~3.5.
// Structure (R14-R17):
//   1 k_argmax_uf block0 zeros stats+ghist; per 64x16 tile: argmax + bg term +
//                 LDS union-find + local flatten -> parent[]=global root seed;
//                 per-block partials + local-link counts (plain stores).
//   2 k_bmerge    ~78K tile-boundary edges: global CAS-unite on seeded parent;
//                 AS link partials; last-arriving block reduces ALL partials ->
//                 scalars (ncomp = cnt - links_local - links_boundary).
//   3 k_phase2    scalars plain; root chase (plain cached, ~1-2 hops); keys in
//                 registers; exact-code hist (ballot-aggregated bin0, 257-pad)
//                 -> per-(blockIdx&7) ghist replica -> arrive -> non-last exit
//                 -> last block: replica-sum + 7-thread scan -> bce+dice.
// ws layout (verified non-overlapping):
//   stats[0,8192) ghist[8192,24576) pcnt[24576,45056) mcnt[45056,53248)
//   pdbl[53248,59392) bcnt[59392,61440).

#define HWMASK (262144 - 1)
#define AL(p) __hip_atomic_load((p), __ATOMIC_RELAXED, __HIP_MEMORY_SCOPE_AGENT)
#define AS(p, v) __hip_atomic_store((p), (v), __ATOMIC_RELAXED, __HIP_MEMORY_SCOPE_AGENT)
#define REL(p, v) __hip_atomic_store((p), (v), __ATOMIC_RELEASE, __HIP_MEMORY_SCOPE_AGENT)
#define ARRIVE(p) __hip_atomic_fetch_add((p), 1u, __ATOMIC_RELAXED, __HIP_MEMORY_SCOPE_AGENT)

// ---- global UF (boundary edges only) -------------------------------------
static __device__ __forceinline__ int ufind(int* p, int x) {
  while (true) {
    int px = p[x];
    if (px == x) return x;
    int g = p[px];
    if (g == px) return px;
    p[x] = g;  // halving: target non-root, value ancestor -> benign
    x = g;
  }
}
static __device__ __forceinline__ int unite(int* p, int a, int b) {
  while (true) {
    a = ufind(p, a); b = ufind(p, b);
    if (a == b) return 0;
    if (a < b) { int old = atomicCAS(&p[b], b, a); if (old == b) return 1; b = old; }
    else       { int old = atomicCAS(&p[a], a, b); if (old == a) return 1; a = old; }
  }
}
// ---- LDS UF (intra-tile) ---------------------------------------------------
static __device__ __forceinline__ int lfind(int* p, int x) {
  while (true) {
    int px = p[x];
    if (px == x) return x;
    int g = p[px];
    if (g == px) return px;
    p[x] = g;
    x = g;
  }
}
static __device__ __forceinline__ int lunite(int* p, int a, int b) {
  while (true) {
    a = lfind(p, a); b = lfind(p, b);
    if (a == b) return 0;
    if (a < b) { int old = atomicCAS(&p[b], b, a); if (old == b) return 1; b = old; }
    else       { int old = atomicCAS(&p[a], a, b); if (old == a) return 1; a = old; }
  }
}

// One 64x16 tile per block; thread t owns 4 px: lx=(t&15)*4, ly=t>>4.
__global__ __launch_bounds__(256, 4) void k_argmax_uf(
    const float* __restrict__ pred, const int* __restrict__ tgt,
    int* __restrict__ parent, unsigned char* __restrict__ pk,
    unsigned* __restrict__ stats, unsigned* __restrict__ pcnt,
    unsigned* __restrict__ mcnt, double* __restrict__ pdbl, int N) {
  __shared__ int slab[1024];
  __shared__ unsigned char scls[1024];
  __shared__ unsigned hc8[8], ht8[8], lcnt[8], hA, hB;
  __shared__ double dred[12];
  int tid = threadIdx.x, bid = blockIdx.x;
  if (bid == 0) {     // zero stats[0..8191] + ghist[16384] = 24576 words
    uint4* z = (uint4*)stats;
    for (int j = tid; j < 6144; j += 256) z[j] = make_uint4(0u, 0u, 0u, 0u);
  }
  if (tid < 8) { hc8[tid] = 0; ht8[tid] = 0; lcnt[tid] = 0; }
  if (tid == 0) { hA = 0; hB = 0; }
  __syncthreads();
  // tile coords: 8 tile-cols x 32 tile-rows per image, 256 tiles/image
  int img = bid >> 8, trow = (bid & 255) >> 3, tcol = bid & 7;
  int ly = tid >> 4, lx4 = (tid & 15) << 2;
  int lj = (ly << 6) + lx4;                       // local idx of first px
  int gy = (trow << 4) + ly, gx = (tcol << 6) + lx4;
  int gi = (img << 18) + (gy << 9) + gx;
  const float* pp = pred + ((size_t)img << 21) + (gy << 9) + gx;
  float4 v[8];
#pragma unroll
  for (int ch = 0; ch < 8; ++ch) v[ch] = *(const float4*)(pp + ((size_t)ch << 18));
  int4 tv = *(const int4*)(tgt + gi);
  int tarr[4] = {tv.x & 7, tv.y & 7, tv.z & 7, tv.w & 7};
  unsigned char pkb[4], carr[4];
  double aI = 0.0, aP = 0.0;
  float prodL = 1.0f;   // product of clipped factors -> ONE logf per thread
  unsigned nA = 0, nB = 0;
  unsigned long long pc0 = 0, pc1 = 0, pt0 = 0, pt1 = 0;  // 16-bit x4 fields
#pragma unroll
  for (int j = 0; j < 4; ++j) {
    float p0 = ((const float*)&v[0])[j];
    float best = p0; int c = 0;
#pragma unroll
    for (int ch = 1; ch < 8; ++ch) {              // first-max == numpy argmax
      float x = ((const float*)&v[ch])[j];
      if (x > best) { best = x; c = ch; }
    }
    int t = tarr[j];
    carr[j] = (unsigned char)c;
    pkb[j] = (unsigned char)(c | (t << 3));
    if (c < 4) pc0 += 1ull << (c << 4); else pc1 += 1ull << ((c - 4) << 4);
    if (t < 4) pt0 += 1ull << (t << 4); else pt1 += 1ull << ((t - 4) << 4);
    if (c == 0) {                                 // continuous bg term
      float pc = fminf(fmaxf(p0, 1e-7f), 1.0f - 1e-7f);
      if (t == 0) { prodL *= pc; aI += (double)p0; }
      else        { prodL *= (1.0f - pc); }
      aP += (double)p0;
    } else { if (t == 0) nA++; else nB++; }       // pv==0 -> constant, count
  }
  double aL = (prodL == 1.0f) ? 0.0 : (double)logf(prodL);
  *(uchar4*)(pk + gi) = make_uchar4(pkb[0], pkb[1], pkb[2], pkb[3]);
  *(uchar4*)(scls + lj) = make_uchar4(carr[0], carr[1], carr[2], carr[3]);
  *(int4*)(slab + lj) = make_int4(lj, lj + 1, lj + 2, lj + 3);
  // wave-reduce packed counters + nA/nB (no per-pixel LDS atomics)
#pragma unroll
  for (int o = 32; o > 0; o >>= 1) {
    pc0 += __shfl_down(pc0, o); pc1 += __shfl_down(pc1, o);
    pt0 += __shfl_down(pt0, o); pt1 += __shfl_down(pt1, o);
    nA += __shfl_down(nA, o);   nB += __shfl_down(nB, o);
  }
  int lane = tid & 63;
  if (lane == 0) {
#pragma unroll
    for (int q = 0; q < 4; ++q) {
      unsigned a = (unsigned)((pc0 >> (q << 4)) & 0xFFFFull);
      unsigned b = (unsigned)((pc1 >> (q << 4)) & 0xFFFFull);
      unsigned c = (unsigned)((pt0 >> (q << 4)) & 0xFFFFull);
      unsigned d = (unsigned)((pt1 >> (q << 4)) & 0xFFFFull);
      if (a) atomicAdd(&hc8[q], a);
      if (b) atomicAdd(&hc8[4 + q], b);
      if (c) atomicAdd(&ht8[q], c);
      if (d) atomicAdd(&ht8[4 + q], d);
    }
    if (nA) atomicAdd(&hA, nA);
    if (nB) atomicAdd(&hB, nB);
  }
  __syncthreads();
  // ---- local UF over intra-tile edges ------------------------------------
#pragma unroll
  for (int k = 0; k < 3; ++k)                     // intra-quad right edges
    if (carr[k] && carr[k] == carr[k + 1] && lunite(slab, lj + k, lj + k + 1))
      atomicAdd(&lcnt[carr[k]], 1u);
  if (lx4 < 60) {                                 // quad-boundary right edge
    unsigned char nc = scls[lj + 4];
    if (carr[3] && carr[3] == nc && lunite(slab, lj + 3, lj + 4))
      atomicAdd(&lcnt[carr[3]], 1u);
  }
  if (ly < 15) {                                  // down edges
#pragma unroll
    for (int k = 0; k < 4; ++k) {
      unsigned char nc = scls[lj + 64 + k];
      if (carr[k] && carr[k] == nc && lunite(slab, lj + k, lj + 64 + k))
        atomicAdd(&lcnt[carr[k]], 1u);
    }
  }
  __syncthreads();
  // ---- local flatten -> global root seed ---------------------------------
  int pout[4];
#pragma unroll
  for (int k = 0; k < 4; ++k) {
    pout[k] = gi + k;
    if (carr[k]) {
      int r = slab[lj + k];
      while (true) { int nx = slab[r]; if (nx == r) break; r = nx; }
      pout[k] = (img << 18) + (((trow << 4) + (r >> 6)) << 9) + (tcol << 6) + (r & 63);
    }
  }
  *(int4*)(parent + gi) = make_int4(pout[0], pout[1], pout[2], pout[3]);
#pragma unroll
  for (int o = 32; o > 0; o >>= 1) {
    aL += __shfl_down(aL, o); aI += __shfl_down(aI, o); aP += __shfl_down(aP, o);
  }
  int wid = tid >> 6;
  if (lane == 0) { dred[wid] = aL; dred[4 + wid] = aI; dred[8 + wid] = aP; }
  __syncthreads();
  // per-block partials: plain stores (boundary flush publishes)
  if (tid < 8) {
    pcnt[bid * 20 + tid]     = hc8[tid];
    pcnt[bid * 20 + 8 + tid] = ht8[tid];
    mcnt[bid * 8 + tid] = lcnt[tid];
  }
  if (tid == 0) {
    pcnt[bid * 20 + 16] = hA; pcnt[bid * 20 + 17] = hB;
    pcnt[bid * 20 + 18] = 0u; pcnt[bid * 20 + 19] = 0u;
    pdbl[bid * 3 + 0] = dred[0] + dred[1] + dred[2] + dred[3];
    pdbl[bid * 3 + 1] = dred[4] + dred[5] + dred[6] + dred[7];
    pdbl[bid * 3 + 2] = dred[8] + dred[9] + dred[10] + dred[11];
  }
}

// Boundary edges: x=63 mod 64 (right) and y=15 mod 16 (down). ~78K edges.
__global__ __launch_bounds__(256) void k_bmerge(
    const unsigned char* __restrict__ pk, int* __restrict__ parent,
    unsigned* __restrict__ stats, const unsigned* __restrict__ pcnt,
    const unsigned* __restrict__ mcnt, unsigned* __restrict__ bcnt,
    int N, int nbam) {
  __shared__ unsigned lcnt[8], tot[26];
  __shared__ int lastM;
  int tid = threadIdx.x, bid = blockIdx.x;
  if (tid < 8) lcnt[tid] = 0;
  __syncthreads();
  int B = N >> 18;
  int Eh = B * 3584;                   // 7 x-boundaries x 512 rows per image
  int E = Eh + B * 15872;              // + 31 y-boundaries x 512 cols
  int gsz = gridDim.x * blockDim.x;
  for (int e = bid * blockDim.x + tid; e < E; e += gsz) {
    int gi1, gi2;
    if (e < Eh) {
      int img = e / 3584, rem = e % 3584;
      int x = ((rem >> 9) << 6) + 63, y = rem & 511;
      gi1 = (img << 18) + (y << 9) + x; gi2 = gi1 + 1;
    } else {
      int e2 = e - Eh;
      int img = e2 / 15872, rem = e2 % 15872;
      int y = ((rem >> 9) << 4) + 15, x = rem & 511;
      gi1 = (img << 18) + (y << 9) + x; gi2 = gi1 + 512;
    }
    int c1 = pk[gi1] & 7;
    if (c1 && c1 == (pk[gi2] & 7) && unite(parent, gi1, gi2))
      atomicAdd(&lcnt[c1], 1u);
  }
  __syncthreads();
  if (tid < 8) AS(&bcnt[bid * 8 + tid], lcnt[tid]);   // -> LLC (same-kernel read)
  __syncthreads();   // drain vmcnt before arrive
  if (tid == 0) lastM = (ARRIVE(&stats[76]) == gridDim.x - 1) ? 1 : 0;
  __syncthreads();
  if (!lastM) return;                                  // no spinning
  // ---- last block: reduce partials + scalars ----------------------------
  unsigned S[26];
#pragma unroll
  for (int k = 0; k < 26; ++k) S[k] = 0u;
  for (int b = tid; b < nbam; b += 256) {
    const unsigned* p = pcnt + b * 20;
#pragma unroll
    for (int k = 0; k < 18; ++k) S[k] += p[k];         // plain: post-boundary
#pragma unroll
    for (int k = 0; k < 8; ++k) S[18 + k] += mcnt[b * 8 + k];  // local links
  }
  for (int b = tid; b < (int)gridDim.x; b += 256)      // boundary links (AL)
#pragma unroll
    for (int k = 0; k < 8; ++k) S[18 + k] += AL(&bcnt[b * 8 + k]);
  if (tid < 26) tot[tid] = 0u;
  __syncthreads();
#pragma unroll
  for (int k = 0; k < 26; ++k) {
    unsigned s = S[k];
#pragma unroll
    for (int o = 32; o > 0; o >>= 1) s += __shfl_down(s, o);
    if ((tid & 63) == 0 && s) atomicAdd(&tot[k], s);
  }
  __syncthreads();
  if (tid != 0) return;
  // scalars (single thread); plain stores -- boundary flush publishes
  float prodf[8]; int last_i = 1; unsigned pb = 0;
  for (int v = 1; v < 8; ++v) {
    unsigned cntv = tot[v];
    unsigned ncv = cntv - tot[18 + v];   // ncomp = cnt - successful links
    prodf[v] = 0.0f;
    if (cntv) {
      prodf[v] = __fmul_rn((float)ncv, (float)last_i);     // exact ref rounding
      pb |= 1u << v;
      last_i += (int)ncv + ((cntv < (unsigned)N) ? 1 : 0); // + has_bg
    }
    stats[24 + v] = __float_as_uint(prodf[v]);
  }
  float ph0 = 0.0f;   // background key (min key: rounding is monotone)
  for (int v = 1; v < 8; ++v) if (pb & (1u << v)) ph0 = __fadd_rn(ph0, prodf[v]);
  unsigned ab = 0;
  for (int t = 0; t < 8; ++t) stats[8 + t] = tot[8 + t];
  for (int t = 1; t < 8; ++t) {
    unsigned n = tot[8 + t];
    stats[48 + t] = n ? ((n - 1) >> 1) : 0u;   // lower-median rank
    if (n) ab |= 1u << t;
  }
  stats[32] = pb; stats[33] = ab;
  stats[34] = tot[16]; stats[35] = tot[17];
  unsigned pbits = __float_as_uint(ph0);
  stats[36] = pbits;
  // key-code window bound: codes in (ph0, ph0+2^20] <= 2^(43-e) + margin
  unsigned c;
  if (pbits == 0) c = 64u;
  else {
    int e = (int)(pbits >> 23) - 127;
    int sh = 43 - e;
    if (sh <= 0) c = 64u;
    else if (sh >= 31) c = 0x7FFFFFFFu;
    else c = (1u << sh) + 64u;
  }
  int bl = 32 - __clz((int)c);
  stats[37] = (bl > 8) ? (unsigned)(bl - 8) : 0u;   // s1 for 8-bit digits
}

// Fallback-path scan: pick bin holding rank krem[t], update prefix.
static __device__ void scan_select(unsigned* __restrict__ stats,
                                   const unsigned* __restrict__ ghist,
                                   unsigned abm, int s_cur, unsigned* lh) {
  int tid = threadIdx.x;
  for (int t = 1; t < 8; ++t) {
    if (!(abm >> t & 1u)) continue;
    int k = (int)AL(&stats[48 + t]);
    unsigned cnt = 0;
#pragma unroll
    for (int r = 0; r < 8; ++r)
      cnt += AL(&ghist[r * 2048 + (t << 8) + tid]);
    lh[tid] = cnt;
    __syncthreads();
    for (int o = 1; o < 256; o <<= 1) {   // inclusive Hillis-Steele
      unsigned v = (tid >= o) ? lh[tid - o] : 0u;
      __syncthreads();
      lh[tid] += v;
      __syncthreads();
    }
    unsigned incl = lh[tid], excl = incl - cnt;
    if ((unsigned)k >= excl && (unsigned)k < incl) {   // unique owner
      atomicOr(&stats[40 + t], ((unsigned)tid) << s_cur);
      AS(&stats[48 + t], (unsigned)(k - (int)excl));
    }
    __syncthreads();
  }
}

static __device__ void finalize_loss(unsigned* __restrict__ stats,
                                     const double* __restrict__ pdbl,
                                     float* __restrict__ out, int N, int nbam,
                                     unsigned ab, double* dred) {
  int tid = threadIdx.x;
  double vL = 0.0, vI = 0.0, vP = 0.0;
  for (int b = tid; b < nbam; b += 256) {
    vL += pdbl[b * 3]; vI += pdbl[b * 3 + 1]; vP += pdbl[b * 3 + 2];
  }
#pragma unroll
  for (int o = 32; o > 0; o >>= 1) {
    vL += __shfl_down(vL, o); vI += __shfl_down(vI, o); vP += __shfl_down(vP, o);
  }
  int wid = tid >> 6, lane = tid & 63;
  if (lane == 0) { dred[wid] = vL; dred[4 + wid] = vI; dred[8 + wid] = vP; }
  __syncthreads();
  if (tid != 0) return;
  vL = dred[0] + dred[1] + dred[2] + dred[3];
  vI = dred[4] + dred[5] + dred[6] + dred[7];
  vP = dred[8] + dred[9] + dred[10] + dred[11];
  double Nd = (double)N;
  const float e32 = 1e-7f;
  const float c1 = 1.0f - e32;
  const float omc1 = 1.0f - c1;
  double lp1 = log((double)c1);
  double lp0 = log((double)e32);
  double l01 = log((double)omc1);
  double l00 = lp1;
  double L = vL + (double)stats[34] * lp0 + (double)stats[35] * l00;
  double res = -L / Nd;                                                // bce_bg
  res += 1.0 - (2.0 * vI + 1.0) / (vP + (double)stats[8] + 1.0);       // dice_bg
  for (int t = 1; t < 8; ++t) {
    if (ab >> t & 1u) {
      double a = (double)AL(&stats[56 + t]);   // n11
      double f = (double)AL(&stats[64 + t]);   // |full_med|
      double n = (double)stats[8 + t];
      double bce = -(a * lp1 + (n - a) * lp0 + (f - a) * l01 + (Nd - n - f + a) * l00) / Nd;
      double dice = 1.0 - (2.0 * a + 1.0) / (f + n + 1.0);
      res += bce + dice;
    }
  }
  int nu = 0;
  for (int t = 0; t < 8; ++t) nu += (stats[8 + t] > 0) ? 1 : 0;
  out[0] = (float)(res / ((double)nu + 1.0));
}

__global__ __launch_bounds__(256, 4) void k_phase2(
    const unsigned char* __restrict__ pk, const int* __restrict__ parent,
    unsigned* __restrict__ stats, unsigned* __restrict__ ghist,
    const double* __restrict__ pdbl, float* __restrict__ out, int N, int nbam) {
  __shared__ unsigned lh[2176];    // main: lh[t*257+bin] (banks differ per t)
  __shared__ float sprod[8];
  __shared__ unsigned sw[32];
  __shared__ double dred[12];
  int tid = threadIdx.x;
  int lane = tid & 63;
  if (tid < 8) sprod[tid] = __uint_as_float(stats[24 + tid]);   // post-boundary
  if (tid == 0) { sw[0] = stats[32]; sw[1] = stats[33]; sw[2] = stats[36]; sw[3] = stats[37]; }
  for (int j = tid; j < 2176; j += 256) lh[j] = 0u;
  __syncthreads();
  unsigned pb = sw[0], ab = sw[1], ph0 = sw[2];
  int s1 = (int)sw[3];
  unsigned rep = (blockIdx.x & 7) * 2048u;
  int n4 = N >> 2;
  // ---- root chase + keys (registers) + exact-code hist -------------------
  unsigned kk[4];
  unsigned char tv8[4], binv[4];
  int i4 = blockIdx.x * blockDim.x + tid;   // one quad per thread
  if (i4 < n4) {
    int i = i4 << 2;
    int4 pr = *(const int4*)(parent + i);
    uchar4 pv = *(const uchar4*)(pk + i);
    int parr[4] = {pr.x, pr.y, pr.z, pr.w};
    unsigned char pa[4] = {pv.x, pv.y, pv.z, pv.w};
#pragma unroll
    for (int j = 0; j < 4; ++j) {
      int c = pa[j] & 7, t = pa[j] >> 3;
      float lab = 0.0f;
      if (c) {
        int x = parr[j];
        while (true) { int nx = parent[x]; if (nx == x) break; x = nx; }
        lab = (float)(x + 1);                    // < 2^24, exact
      }
      float ph = 0.0f;
#pragma unroll
      for (int v = 1; v < 8; ++v) {              // exact numpy op order
        if (pb & (1u << v)) {
          float term = sprod[v];
          if (c == v) term = __fadd_rn(lab, term);
          ph = __fadd_rn(ph, term);
        }
      }
      unsigned kb = __float_as_uint(ph);
      kk[j] = kb; tv8[j] = (unsigned char)t;
      unsigned off = kb - ph0;                   // >= 0 by monotonicity
      unsigned bin = off >> s1;
      if (bin > 255u) bin = 255u;
      binv[j] = (unsigned char)bin;
    }
  } else {
#pragma unroll
    for (int j = 0; j < 4; ++j) { kk[j] = 0xFFFFFFFFu; tv8[j] = 0; binv[j] = 255; }
  }
  // hist adds: ballot-aggregate bin==0 (bg majority); rare bins individually.
#pragma unroll
  for (int e = 0; e < 4; ++e) {
    bool act = (i4 < n4);
    unsigned bin = binv[e];
    int t = tv8[e];
    bool b0 = act && (bin == 0u);
    unsigned long long m0 = __ballot(b0);
    if (b0) {
      if (lane == (int)__ffsll(m0) - 1) atomicAdd(&lh[0], (unsigned)__popcll(m0));
    } else if (act) {
      atomicAdd(&lh[bin], 1u);
    }
#pragma unroll
    for (int tt = 1; tt < 8; ++tt) {
      if (!(ab >> tt & 1u)) continue;
      unsigned long long mt = __ballot(b0 && t == tt);
      if (mt && lane == (int)__ffsll(mt) - 1)
        atomicAdd(&lh[tt * 257], (unsigned)__popcll(mt));
    }
    if (act && bin != 0u && t && (ab >> t & 1u))
      atomicAdd(&lh[t * 257 + bin], 1u);
  }
  __syncthreads();
  for (int j = tid; j < 2048; j += 256) {        // flush: 257-stride -> packed
    unsigned v = lh[(j >> 8) * 257 + (j & 255)];
    if (v) atomicAdd(&ghist[rep + j], v);
  }
  __syncthreads();
  if (tid == 0) sw[4] = (ARRIVE(&stats[77]) == gridDim.x - 1) ? 1u : 0u;
  __syncthreads();
  if (s1 == 0) {
    // ==== COMMON PATH: bins are exact codes ================================
    if (!sw[4]) return;                          // non-last blocks exit
    for (int j = tid; j < 2048; j += 256) {      // parallel 8-replica sum
      unsigned s = 0;
#pragma unroll
      for (int r = 0; r < 8; ++r) s += AL(&ghist[r * 2048 + j]);
      lh[j] = s;                                 // packed (t<<8|bin) layout
    }
    __syncthreads();
    if (tid >= 1 && tid < 8 && (ab >> tid & 1u)) {   // 7 independent scanners
      int t = tid;
      unsigned k = stats[48 + t];
      unsigned cum = 0;
      int mb = 255;
      for (int b = 0; b < 256; ++b) {
        unsigned c = lh[(t << 8) + b];
        if (cum + c > k) { mb = b; break; }
        cum += c;
      }
      AS(&stats[56 + t], lh[(t << 8) + mb]);     // n11 = hist[t][med_bin]
      AS(&stats[64 + t], lh[mb]);                // nfm = histAll[med_bin]
    }
    __syncthreads();                             // drain AS before AL reads
    finalize_loss(stats, pdbl, out, N, nbam, ab, dred);
    return;
  }
  // ==== FALLBACK (s1 > 0): multi-pass radix + med-match, spin barriers ====
  if (sw[4]) {
    scan_select(stats, ghist, ab, s1, lh);
    for (int j = tid; j < 16384; j += 256) AS(&ghist[j], 0u);
    __syncthreads();
    if (tid == 0) REL(&stats[39], 1u);
  } else {
    if (tid == 0) while (AL(&stats[39]) < 1u) __builtin_amdgcn_s_sleep(2);
    __syncthreads();
  }
  for (int pass = 2; pass <= 4; ++pass) {
    int sprev = s1 - 8 * (pass - 2); if (sprev < 0) sprev = 0;
    int scur  = s1 - 8 * (pass - 1); if (scur  < 0) scur  = 0;
    unsigned maskhi = 0xFFFFFFFFu << sprev;
    if (tid < 8) sw[8 + tid] = AL(&stats[40 + tid]);
    for (int j = tid; j < 2048; j += 256) lh[j] = 0u;
    __syncthreads();
#pragma unroll
    for (int e = 0; e < 4; ++e) {
      int t = tv8[e];
      if (t && (ab >> t & 1u)) {
        unsigned off = kk[e] - ph0;
        if (((off ^ sw[8 + t]) & maskhi) == 0u)
          atomicAdd(&lh[(t << 8) | ((off >> scur) & 255u)], 1u);
      }
    }
    __syncthreads();
    for (int j = tid; j < 2048; j += 256) {
      unsigned v = lh[j];
      if (v) atomicAdd(&ghist[rep + j], v);
    }
    __syncthreads();
    if (tid == 0) sw[5] = (ARRIVE(&stats[76 + pass]) == gridDim.x - 1) ? 1u : 0u;
    __syncthreads();
    if (sw[5]) {
      scan_select(stats, ghist, ab, scur, lh);
      if (scur > 0)
        for (int j = tid; j < 16384; j += 256) AS(&ghist[j], 0u);
      __syncthreads();
      if (tid == 0) REL(&stats[39], (unsigned)pass);
    } else {
      if (tid == 0)
        while (AL(&stats[39]) < (unsigned)pass) __builtin_amdgcn_s_sleep(2);
      __syncthreads();
    }
    if (scur == 0) break;
  }
  // med-match counts from register keys
  if (tid < 16) lh[tid] = 0u;
  if (tid < 8) sw[20 + tid] = ph0 + AL(&stats[40 + tid]);
  __syncthreads();
#pragma unroll
  for (int e = 0; e < 4; ++e) {
    unsigned kb = kk[e];
    int t = tv8[e];
#pragma unroll
    for (int tt = 1; tt < 8; ++tt) {
      if ((ab >> tt & 1u) && kb == sw[20 + tt]) {
        atomicAdd(&lh[8 + tt], 1u);
        if (t == tt) atomicAdd(&lh[tt], 1u);
      }
    }
  }
  __syncthreads();
  if (tid >= 1 && tid < 8) {
    if (lh[8 + tid]) atomicAdd(&stats[64 + tid], lh[8 + tid]);   // nfm
    if (lh[tid])     atomicAdd(&stats[56 + tid], lh[tid]);       // n11
  }
  __syncthreads();
  if (tid == 0) sw[6] = (ARRIVE(&stats[84]) == gridDim.x - 1) ? 1u : 0u;
  __syncthreads();
  if (!sw[6]) return;
  finalize_loss(stats, pdbl, out, N, nbam, ab, dred);
}

extern "C" void kernel_launch(void* const* d_in, const int* in_sizes, int n_in,
                              void* d_out, int out_size, void* d_ws, size_t ws_size,
                              hipStream_t stream) {
  const float* pred = (const float*)d_in[0];   // [B,8,512,512] f32
  const int* tgt = (const int*)d_in[1];        // [B,1,512,512] i32
  int N = in_sizes[1];                         // B*H*W, H=W=512
  char* ws = (char*)d_ws;
  int* parent = (int*)ws;
  unsigned char* pk = (unsigned char*)(ws + (size_t)N * 4);
  unsigned* stats = (unsigned*)(ws + (size_t)N * 5);
  unsigned* ghist = stats + 8192;
  unsigned* pcnt = stats + 24576;
  unsigned* mcnt = stats + 45056;              // [45056, 53248)
  double* pdbl = (double*)(stats + 53248);     // [53248, 59392)
  unsigned* bcnt = stats + 59392;              // [59392, 61440)
  float* out = (float*)d_out;
  int nbam = N >> 10;                          // 64x16 tiles (1024 px) = 1024
  int nblk2 = ((N >> 2) + 255) >> 8;           // one quad per thread

  k_argmax_uf<<<nbam, 256, 0, stream>>>(pred, tgt, parent, pk, stats, pcnt, mcnt, pdbl, N);
  k_bmerge<<<256, 256, 0, stream>>>(pk, parent, stats, pcnt, mcnt, bcnt, N, nbam);
  k_phase2<<<nblk2, 256, 0, stream>>>(pk, parent, stats, ghist, pdbl, out, N, nbam);
}